// Round 16
// baseline (111.357 us; speedup 1.0000x reference)
//
#include <hip/hip_runtime.h>
#include <math.h>

typedef __attribute__((ext_vector_type(8))) short short8;
typedef __attribute__((ext_vector_type(8))) _Float16 h16x8;
typedef __attribute__((ext_vector_type(4))) float f32x4;

#define BB 8
#define CC 256
#define OO 256
#define HH 56
#define WW 56
#define HWH 3136
#define RED 16

__device__ inline unsigned short f2h(float f) {
    _Float16 h = (_Float16)f;
    return __builtin_bit_cast(unsigned short, h);
}
__device__ inline float h2f(unsigned short u) {
    return (float)__builtin_bit_cast(_Float16, u);
}
__device__ inline unsigned pkrtz(float lo, float hi) {
    return __builtin_bit_cast(unsigned, __builtin_amdgcn_cvt_pkrtz(lo, hi));
}
__device__ inline float fast_tanh(float x) {
    float e = __expf(2.0f * x);
    return 1.0f - 2.0f / (e + 1.0f);
}
__device__ inline void gl2lds16(const void* g, void* l) {
    __builtin_amdgcn_global_load_lds((const __attribute__((address_space(1))) unsigned int*)g,
                                     (__attribute__((address_space(3))) unsigned int*)l, 16, 0, 0);
}
// packed fp16 helpers: broadcast src1 lo/hi half via op_sel
__device__ inline unsigned pkmul_lo(unsigned a, unsigned b) {
    unsigned d;
    asm("v_pk_mul_f16 %0, %1, %2 op_sel:[0,0] op_sel_hi:[1,0]" : "=v"(d) : "v"(a), "v"(b));
    return d;
}
__device__ inline unsigned pkfma_hi(unsigned a, unsigned b, unsigned c) {
    unsigned d;
    asm("v_pk_fma_f16 %0, %1, %2, %3 op_sel:[0,1,0] op_sel_hi:[1,1,1]" : "=v"(d) : "v"(a), "v"(b), "v"(c));
    return d;
}
__device__ inline unsigned pkfma_lo(unsigned a, unsigned b, unsigned c) {
    unsigned d;
    asm("v_pk_fma_f16 %0, %1, %2, %3 op_sel:[0,0,0] op_sel_hi:[1,0,1]" : "=v"(d) : "v"(a), "v"(b), "v"(c));
    return d;
}
__device__ inline unsigned pkmul(unsigned a, unsigned b) {
    unsigned d;
    asm("v_pk_mul_f16 %0, %1, %2" : "=v"(d) : "v"(a), "v"(b));
    return d;
}
// bilinear blend of one 8-ch item (4 packed pairs) + per-channel scale -> 16B LDS write
__device__ inline void blend16(uint4 q0, uint4 q1, uint4 q2, uint4 q3,
                               uint2 cw, uint4 sp, char* dst) {
    unsigned o0 = pkmul_lo(q0.x, cw.x); o0 = pkfma_hi(q1.x, cw.x, o0);
    o0 = pkfma_lo(q2.x, cw.y, o0); o0 = pkfma_hi(q3.x, cw.y, o0); o0 = pkmul(o0, sp.x);
    unsigned o1 = pkmul_lo(q0.y, cw.x); o1 = pkfma_hi(q1.y, cw.x, o1);
    o1 = pkfma_lo(q2.y, cw.y, o1); o1 = pkfma_hi(q3.y, cw.y, o1); o1 = pkmul(o1, sp.y);
    unsigned o2 = pkmul_lo(q0.z, cw.x); o2 = pkfma_hi(q1.z, cw.x, o2);
    o2 = pkfma_lo(q2.z, cw.y, o2); o2 = pkfma_hi(q3.z, cw.y, o2); o2 = pkmul(o2, sp.z);
    unsigned o3 = pkmul_lo(q0.w, cw.x); o3 = pkfma_hi(q1.w, cw.x, o3);
    o3 = pkfma_lo(q2.w, cw.y, o3); o3 = pkfma_hi(q3.w, cw.y, o3); o3 = pkmul(o3, sp.w);
    *(uint4*)dst = make_uint4(o0, o1, o2, o3);
}

// ---------------- prep_xt + weight prep merged ----------------
__global__ __launch_bounds__(256) void prep_xt(const float* __restrict__ x,
                                               const float* __restrict__ w_conv,
                                               const float* __restrict__ w_off,
                                               unsigned short* __restrict__ x_t,
                                               unsigned short* __restrict__ wbf,
                                               unsigned short* __restrict__ wbo,
                                               float* __restrict__ y) {
    int blk = blockIdx.x;
    int tid = threadIdx.x;
    if (blk >= 1568) {
        int wb = blk - 1568;
        if (wb < 288) {
            int idx = wb * 256 + tid;            // 73728 items
            int lane = idx & 63;
            int f = (idx >> 6) & 3;
            int og = (idx >> 8) & 7;
            int t = idx >> 11;                   // 0..35
            int kk = t >> 2, cc = t & 3;
            int n = f >> 1, kh = f & 1;
            int o = og * 32 + n * 16 + (lane & 15);
            int cb2 = cc * 64 + kh * 32 + ((lane >> 4) << 3);
            short8 r;
            #pragma unroll
            for (int e = 0; e < 8; ++e) r[e] = (short)f2h(w_conv[(size_t)(o * 256 + cb2 + e) * 9 + kk]);
            *(short8*)(wbf + (size_t)idx * 8) = r;
        } else {
            int idx = (wb - 288) * 256 + tid;    // 9216
            int g = idx & 7;
            int o = (idx >> 3) & 31;
            int t = idx >> 8;
            int kk = t >> 2, cc = t & 3;
            int dst = (((o * 128 + g * 16) ^ ((o & 7) << 4)) >> 1);
            short8 r;
            #pragma unroll
            for (int e = 0; e < 8; ++e) {
                int c = cc * 64 + g * 8 + e;
                r[e] = (o < 18) ? (short)f2h(w_off[(size_t)(o * 256 + c) * 9 + kk]) : (short)0;
            }
            *(short8*)(wbo + (size_t)t * 2048 + dst) = r;
        }
        return;
    }
    __shared__ float t[64][65];
    int ct = blk & 3;
    int hwt = (blk >> 2) % 49;
    int b = blk / (4 * 49);
    int c0 = ct * 64, hw0 = hwt * 64;
    const float* xb = x + ((size_t)(b * CC + c0)) * HWH + hw0;
    #pragma unroll
    for (int it = 0; it < 16; ++it) {
        int idx = it * 256 + tid;
        int c = idx >> 6, px = idx & 63;
        t[c][px] = xb[(size_t)c * HWH + px];
    }
    __syncthreads();
    unsigned short* xo = x_t + ((size_t)(b * HWH + hw0)) * CC + c0;
    #pragma unroll
    for (int it = 0; it < 16; ++it) {
        int idx = it * 256 + tid;
        int px = idx >> 6, c = idx & 63;
        xo[(size_t)px * CC + c] = f2h(t[c][px]);
    }
    int c = tid >> 2, seg = tid & 3;
    float sum = 0.f;
    #pragma unroll
    for (int i = 0; i < 16; ++i) sum += t[c][seg * 16 + i];
    sum += __shfl_down(sum, 1);
    sum += __shfl_down(sum, 2);
    if (seg == 0) atomicAdd(&y[b * 256 + c0 + c], sum);
}

// inline SE: compute s[256] for batch b into s_out (LDS), using first 256 threads.
__device__ inline void se_inline(int tid, int b, const float* __restrict__ y,
                                 const float* __restrict__ fc1, const float* __restrict__ fc2,
                                 float* __restrict__ h_lds, float* __restrict__ s_out) {
    if (tid < 256) {
        int r = tid >> 4, cseg = tid & 15;
        float part = 0.f;
        #pragma unroll
        for (int i = 0; i < 16; ++i)
            part += y[b * 256 + cseg * 16 + i] * fc1[r * 256 + cseg * 16 + i];
        part += __shfl_down(part, 8);
        part += __shfl_down(part, 4);
        part += __shfl_down(part, 2);
        part += __shfl_down(part, 1);
        if (cseg == 0) h_lds[r] = fmaxf(part * (1.0f / HWH), 0.f);
    }
    __syncthreads();
    if (tid < 256) {
        float acc = 0.f;
        #pragma unroll
        for (int rr = 0; rr < 16; ++rr) acc += h_lds[rr] * fc2[tid * 16 + rr];
        s_out[tid] = 1.0f / (1.0f + __expf(-acc));
    }
}

// ---------------- offset conv (fp16 MFMA) + fused SE + fused coord precompute ----------------
__global__ __launch_bounds__(256) void offset_mfma(const unsigned short* __restrict__ x_t,
                                                   const float* __restrict__ y,
                                                   const float* __restrict__ fc1,
                                                   const float* __restrict__ fc2,
                                                   const unsigned short* __restrict__ wbo,
                                                   const float* __restrict__ b_off,
                                                   int4* __restrict__ ci, uint2* __restrict__ cfh) {
    __shared__ __align__(16) char As[4][4096];
    __shared__ __align__(16) char Bs[4][4096];
    __shared__ float red[128 * 8];
    __shared__ float obuf[18 * 32];
    __shared__ float s_lds[256];
    __shared__ float h_lds[16];
    int blk = blockIdx.x;
    blk = (blk & 7) * 98 + (blk >> 3);
    int b = blk / 98;
    int hw0 = (blk % 98) * 32;
    int tid = threadIdx.x;
    int lane = tid & 63, wv = tid >> 6;
    int ks = wv >> 1, m = wv & 1;
    int r0 = lane & 15, kb = (lane >> 4) << 4;
    int px = tid >> 3, c8 = tid & 7;
    int hwp = hw0 + px;
    int hp = hwp / 56, wp_ = hwp - hp * 56;
    int awoff = (px * 128 + c8 * 16) ^ ((px & 7) << 4);
    f32x4 zero = {0.f, 0.f, 0.f, 0.f};
    f32x4 acc[2] = {zero, zero};

    se_inline(tid, b, y, fc1, fc2, h_lds, s_lds);
    __syncthreads();

    auto buildA = [&](int q, int r, int buf) {
        int t = q * 18 + r;
        int kk = t >> 2, cc = t & 3;
        int hh = hp + kk / 3 - 1, ww = wp_ + kk % 3 - 1;
        short8 v = {0, 0, 0, 0, 0, 0, 0, 0};
        if (hh >= 0 && hh < 56 && ww >= 0 && ww < 56)
            v = *(const short8*)(x_t + (((size_t)(b * HWH + hh * 56 + ww)) << 8) + cc * 64 + c8 * 8);
        const float* sp_ = &s_lds[cc * 64 + c8 * 8];
        unsigned p0 = pkrtz(h2f((unsigned short)v[0]) * sp_[0], h2f((unsigned short)v[1]) * sp_[1]);
        unsigned p1 = pkrtz(h2f((unsigned short)v[2]) * sp_[2], h2f((unsigned short)v[3]) * sp_[3]);
        unsigned p2 = pkrtz(h2f((unsigned short)v[4]) * sp_[4], h2f((unsigned short)v[5]) * sp_[5]);
        unsigned p3 = pkrtz(h2f((unsigned short)v[6]) * sp_[6], h2f((unsigned short)v[7]) * sp_[7]);
        *(uint4*)(As[q * 2 + buf] + awoff) = make_uint4(p0, p1, p2, p3);
    };
    auto stageB = [&](int q, int r, int buf) {
        int t = q * 18 + r;
        gl2lds16(wbo + (size_t)t * 2048 + tid * 8, Bs[q * 2 + buf] + (tid >> 6) * 1024);
    };

    stageB(0, 0, 0); stageB(1, 0, 0);
    buildA(0, 0, 0); buildA(1, 0, 0);
    __syncthreads();

    #pragma unroll 2
    for (int r = 0; r < 18; ++r) {
        int cur = r & 1;
        if (r < 17) {
            stageB(0, r + 1, cur ^ 1); stageB(1, r + 1, cur ^ 1);
            buildA(0, r + 1, cur ^ 1); buildA(1, r + 1, cur ^ 1);
        }
        h16x8 a[2];
        #pragma unroll
        for (int kh = 0; kh < 2; ++kh) {
            int row = m * 16 + r0;
            int ao = (row * 128 + kh * 64 + kb) ^ ((row & 7) << 4);
            a[kh] = __builtin_bit_cast(h16x8, *(const short8*)(As[ks * 2 + cur] + ao));
        }
        #pragma unroll
        for (int n = 0; n < 2; ++n)
            #pragma unroll
            for (int kh = 0; kh < 2; ++kh) {
                int brow = n * 16 + r0;
                int bo = (brow * 128 + kh * 64 + kb) ^ ((brow & 7) << 4);
                h16x8 bv = __builtin_bit_cast(h16x8, *(const short8*)(Bs[ks * 2 + cur] + bo));
                acc[n] = __builtin_amdgcn_mfma_f32_16x16x32_f16(a[kh], bv, acc[n], 0, 0, 0);
            }
        __syncthreads();
    }

    if (ks == 1) {
        #pragma unroll
        for (int n = 0; n < 2; ++n)
            *(f32x4*)&red[(m * 64 + lane) * 8 + n * 4] = acc[n];
    }
    __syncthreads();
    if (ks == 0) {
        #pragma unroll
        for (int n = 0; n < 2; ++n) {
            f32x4 o2 = *(const f32x4*)&red[(m * 64 + lane) * 8 + n * 4];
            acc[n] += o2;
            int o = n * 16 + r0;
            if (o < 18) {
                float bia = b_off[o];
                #pragma unroll
                for (int j = 0; j < 4; ++j)
                    obuf[o * 32 + m * 16 + ((lane >> 4) << 2) + j] = acc[n][j] + bia;
            }
        }
    }
    __syncthreads();
    // ---- fused coords: 32px x 9kk ----
    for (int i = tid; i < 288; i += 256) {
        int pxi = i & 31, kk = i >> 5;
        int hw = hw0 + pxi;
        int h = hw / 56, w = hw - h * 56;
        float dy = obuf[(kk * 2) * 32 + pxi];
        float dx = obuf[(kk * 2 + 1) * 32 + pxi];
        float ys = (float)(h - 1 + kk / 3) + dy;
        float xs = (float)(w - 1 + kk % 3) + dx;
        float y0f = floorf(ys), x0f = floorf(xs);
        float wy = ys - y0f, wx = xs - x0f;
        int y0 = (int)y0f, x0 = (int)x0f;
        int bi[4]; float wt[4];
        #pragma unroll
        for (int j = 0; j < 4; ++j) {
            int yj = y0 + (j >> 1), xj = x0 + (j & 1);
            bool val = yj >= 0 && yj < 56 && xj >= 0 && xj < 56;
            int yc = min(max(yj, 0), 55), xc = min(max(xj, 0), 55);
            wt[j] = val ? ((j >> 1) ? wy : 1.f - wy) * ((j & 1) ? wx : 1.f - wx) : 0.f;
            bi[j] = (b * HWH + yc * 56 + xc) << 8;
        }
        int idx = (b * 9 + kk) * HWH + hw;
        ci[idx] = make_int4(bi[0], bi[1], bi[2], bi[3]);
        cfh[idx] = make_uint2(pkrtz(wt[0], wt[1]), pkrtz(wt[2], wt[3]));
    }
}

// ---------------- deformable conv: 392 blocks x 512 thr, 64px x 256o, fused SE ----------------
// r16: wave tile 32px x 64o (wm=og>>2, wn=og&3) -> A LDS reads halve (4/wave/phase);
// B fragments 8/wave from global (L2-broadcast). r14 4-buffer pipeline otherwise.
__global__ __launch_bounds__(512) void deform_mfma(const unsigned short* __restrict__ x_t,
                                                   const float* __restrict__ y,
                                                   const float* __restrict__ fc1,
                                                   const float* __restrict__ fc2,
                                                   const int4* __restrict__ ci,
                                                   const uint2* __restrict__ cfh,
                                                   const unsigned short* __restrict__ wbf,
                                                   const float* __restrict__ b_conv,
                                                   float* __restrict__ out) {
    __shared__ __align__(16) char As[32768];     // 4 x 8KB (64px x 128B)
    __shared__ __align__(16) float s_buf[256];
    __shared__ float h_lds[16];
    int blk = blockIdx.x;
    blk = (blk & 7) * 49 + (blk >> 3);           // bijective XCD swizzle (392 = 8*49)
    int b = blk / 49;
    int hw0 = (blk % 49) * 64;
    int tid = threadIdx.x;
    int lane = tid & 63, og = tid >> 6;
    int wm = og >> 2, wn = og & 3;               // wave tile: rows wm*32..+31, cols wn*64..+63
    int px = tid >> 3, cg = tid & 7;             // A-build: 64px x 8 groups of 8ch (16B)
    int r0 = lane & 15, kb = (lane >> 4) << 4;
    int awoff = px * 128 + (cg * 16 ^ ((px & 7) << 4));
    int cidx0 = b * 9 * HWH + hw0 + px;
    const unsigned short* wbB = wbf + (wn * 2) * 2048 + lane * 8;

    se_inline(tid, b, y, fc1, fc2, h_lds, s_buf);
    __syncthreads();

    uint4 sp4[4];
    #pragma unroll
    for (int cc = 0; cc < 4; ++cc) {
        float4 s0 = *(const float4*)&s_buf[cc * 64 + cg * 8];
        float4 s1 = *(const float4*)&s_buf[cc * 64 + cg * 8 + 4];
        sp4[cc] = make_uint4(pkrtz(s0.x, s0.y), pkrtz(s0.z, s0.w), pkrtz(s1.x, s1.y), pkrtz(s1.z, s1.w));
    }

    f32x4 zero = {0.f, 0.f, 0.f, 0.f};
    f32x4 acc[2][4];
    #pragma unroll
    for (int m = 0; m < 2; ++m)
        #pragma unroll
        for (int n = 0; n < 4; ++n) acc[m][n] = zero;

    int4 cbL = ci[cidx0];
    uint2 cwB = cfh[cidx0];
    int4 cbN = ci[cidx0 + HWH];
    uint2 cwM = cfh[cidx0 + HWH];
    uint2 cwP = cwM;

    uint4 crn0[4], crn1[4];
    short8 bv[8];
    const unsigned short* wbK = wbB + 16384;     // ptr to B(1)

    // ---- prologue: blend A(0),A(1) -> As[0],As[1]; crn0<-cc2, crn1<-cc3; bv(0) ----
    {
        uint4 q[4];
        int c00 = cg * 8;
        q[0] = *(const uint4*)(x_t + cbL.x + c00);
        q[1] = *(const uint4*)(x_t + cbL.y + c00);
        q[2] = *(const uint4*)(x_t + cbL.z + c00);
        q[3] = *(const uint4*)(x_t + cbL.w + c00);
        int c02 = 128 + cg * 8;
        crn0[0] = *(const uint4*)(x_t + cbL.x + c02);
        crn0[1] = *(const uint4*)(x_t + cbL.y + c02);
        crn0[2] = *(const uint4*)(x_t + cbL.z + c02);
        crn0[3] = *(const uint4*)(x_t + cbL.w + c02);
        int c03 = 192 + cg * 8;
        crn1[0] = *(const uint4*)(x_t + cbL.x + c03);
        crn1[1] = *(const uint4*)(x_t + cbL.y + c03);
        crn1[2] = *(const uint4*)(x_t + cbL.z + c03);
        crn1[3] = *(const uint4*)(x_t + cbL.w + c03);
        #pragma unroll
        for (int f = 0; f < 8; ++f)
            bv[f] = *(const short8*)(wbB + (f >> 2) * 2048 + (f & 3) * 512);
        blend16(q[0], q[1], q[2], q[3], cwB, sp4[0], As + awoff);
        int c01 = 64 + cg * 8;
        q[0] = *(const uint4*)(x_t + cbL.x + c01);
        q[1] = *(const uint4*)(x_t + cbL.y + c01);
        q[2] = *(const uint4*)(x_t + cbL.z + c01);
        q[3] = *(const uint4*)(x_t + cbL.w + c01);
        blend16(q[0], q[1], q[2], q[3], cwB, sp4[1], As + 8192 + awoff);
    }
    __syncthreads();

// phase p = kk*4 + CCc. bv[n*2+kh] covers o = wn*64 + (n>>1)*32 + (n&1)*16.
#define PHASE(CCV, CRN) { \
    constexpr int CCc = (CCV); \
    if (CCc == 0) cbL = cbN; \
    h16x8 a_[2][2]; \
    { constexpr int tb_ = CCc * 8192; \
      _Pragma("unroll") for (int m_ = 0; m_ < 2; ++m_) \
      _Pragma("unroll") for (int kh_ = 0; kh_ < 2; ++kh_) { \
        int row_ = wm * 32 + m_ * 16 + r0; \
        int ao_ = row_ * 128 + ((kh_ * 64 + kb) ^ ((row_ & 7) << 4)); \
        a_[m_][kh_] = __builtin_bit_cast(h16x8, *(const short8*)(As + tb_ + ao_)); } } \
    __builtin_amdgcn_s_setprio(1); \
    _Pragma("unroll") for (int n_ = 0; n_ < 4; ++n_) \
      _Pragma("unroll") for (int kh_ = 0; kh_ < 2; ++kh_) \
        _Pragma("unroll") for (int m_ = 0; m_ < 2; ++m_) \
          acc[m_][n_] = __builtin_amdgcn_mfma_f32_16x16x32_f16(a_[m_][kh_], __builtin_bit_cast(h16x8, bv[n_ * 2 + kh_]), acc[m_][n_], 0, 0, 0); \
    __builtin_amdgcn_s_setprio(0); \
    if (kk < 8 || CCc < 3) { \
        _Pragma("unroll") for (int f_ = 0; f_ < 8; ++f_) \
            bv[f_] = *(const short8*)(wbK + (f_ >> 2) * 2048 + (f_ & 3) * 512); } \
    wbK += 16384; \
    if (CCc == 2) { cwB = cwM; cwM = cwP; } \
    if (kk < 8 || CCc < 2) { \
        blend16(CRN[0], CRN[1], CRN[2], CRN[3], cwB, sp4[(CCc + 2) & 3], \
                As + ((CCc + 2) & 3) * 8192 + awoff); } \
    if (kk < 8) { \
        constexpr int c0_ = CCc * 64; \
        CRN[0] = *(const uint4*)(x_t + cbL.x + c0_ + cg * 8); \
        CRN[1] = *(const uint4*)(x_t + cbL.y + c0_ + cg * 8); \
        CRN[2] = *(const uint4*)(x_t + cbL.z + c0_ + cg * 8); \
        CRN[3] = *(const uint4*)(x_t + cbL.w + c0_ + cg * 8); } \
    if (CCc == 1 && kk <= 6) { \
        int cidx = cidx0 + (kk + 2) * HWH; \
        cbN = ci[cidx]; cwP = cfh[cidx]; } \
    if (CCc & 1) __syncthreads(); }

    #pragma unroll 1
    for (int kk = 0; kk < 9; ++kk) {
        PHASE(0, crn0);
        PHASE(1, crn1);
        PHASE(2, crn0);
        PHASE(3, crn1);
    }
#undef PHASE

    // ---- epilogue: bias + tanh, NCHW float4 stores ----
    #pragma unroll
    for (int n = 0; n < 4; ++n) {
        int o = wn * 64 + (n >> 1) * 32 + (n & 1) * 16 + r0;
        float bia = b_conv[o];
        #pragma unroll
        for (int m = 0; m < 2; ++m) {
            int pxo = hw0 + wm * 32 + m * 16 + ((lane >> 4) << 2);
            float4 v;
            v.x = fast_tanh(acc[m][n][0] + bia);
            v.y = fast_tanh(acc[m][n][1] + bia);
            v.z = fast_tanh(acc[m][n][2] + bia);
            v.w = fast_tanh(acc[m][n][3] + bia);
            *(float4*)(out + ((size_t)(b * OO + o)) * HWH + pxo) = v;
        }
    }
}

extern "C" void kernel_launch(void* const* d_in, const int* in_sizes, int n_in,
                              void* d_out, int out_size, void* d_ws, size_t ws_size,
                              hipStream_t stream) {
    const float* x      = (const float*)d_in[0];
    const float* w_off  = (const float*)d_in[1];
    const float* b_off  = (const float*)d_in[2];
    const float* w_conv = (const float*)d_in[3];
    const float* b_conv = (const float*)d_in[4];
    const float* fc1    = (const float*)d_in[5];
    const float* fc2    = (const float*)d_in[6];
    float* out = (float*)d_out;
    float* ws  = (float*)d_ws;

    float* y = ws;                                             // 2048 f32
    unsigned short* x_t = (unsigned short*)(y + 2048);         // 6,422,528 shorts (fp16)
    unsigned short* wbo = x_t + 6422528;                       // 73,728 shorts
    unsigned short* wbf = wbo + 73728;                         // 589,824 shorts (36-phase frag layout)
    int4*  ci  = (int4*)(wbf + 589824);                        // 225,792 int4
    uint2* cfh = (uint2*)(ci + 225792);                        // 225,792 uint2

    hipMemsetAsync(y, 0, 2048 * sizeof(float), stream);
    prep_xt<<<1892, 256, 0, stream>>>(x, w_conv, w_off, x_t, wbf, wbo, y);
    offset_mfma<<<BB * 98, 256, 0, stream>>>(x_t, y, fc1, fc2, wbo, b_off, ci, cfh);
    deform_mfma<<<BB * 49, 512, 0, stream>>>(x_t, y, fc1, fc2, ci, cfh, wbf, b_conv, out);
}

// Round 17
// 99.045 us; speedup vs baseline: 1.1243x; 1.1243x over previous
//
#include <hip/hip_runtime.h>
#include <math.h>

typedef __attribute__((ext_vector_type(8))) short short8;
typedef __attribute__((ext_vector_type(8))) _Float16 h16x8;
typedef __attribute__((ext_vector_type(4))) float f32x4;

#define BB 8
#define CC 256
#define OO 256
#define HH 56
#define WW 56
#define HWH 3136
#define RED 16

__device__ inline unsigned short f2h(float f) {
    _Float16 h = (_Float16)f;
    return __builtin_bit_cast(unsigned short, h);
}
__device__ inline float h2f(unsigned short u) {
    return (float)__builtin_bit_cast(_Float16, u);
}
__device__ inline unsigned pkrtz(float lo, float hi) {
    return __builtin_bit_cast(unsigned, __builtin_amdgcn_cvt_pkrtz(lo, hi));
}
__device__ inline float fast_tanh(float x) {
    float e = __expf(2.0f * x);
    return 1.0f - 2.0f / (e + 1.0f);
}
__device__ inline void gl2lds16(const void* g, void* l) {
    __builtin_amdgcn_global_load_lds((const __attribute__((address_space(1))) unsigned int*)g,
                                     (__attribute__((address_space(3))) unsigned int*)l, 16, 0, 0);
}
// packed fp16 helpers: broadcast src1 lo/hi half via op_sel
__device__ inline unsigned pkmul_lo(unsigned a, unsigned b) {
    unsigned d;
    asm("v_pk_mul_f16 %0, %1, %2 op_sel:[0,0] op_sel_hi:[1,0]" : "=v"(d) : "v"(a), "v"(b));
    return d;
}
__device__ inline unsigned pkfma_hi(unsigned a, unsigned b, unsigned c) {
    unsigned d;
    asm("v_pk_fma_f16 %0, %1, %2, %3 op_sel:[0,1,0] op_sel_hi:[1,1,1]" : "=v"(d) : "v"(a), "v"(b), "v"(c));
    return d;
}
__device__ inline unsigned pkfma_lo(unsigned a, unsigned b, unsigned c) {
    unsigned d;
    asm("v_pk_fma_f16 %0, %1, %2, %3 op_sel:[0,0,0] op_sel_hi:[1,0,1]" : "=v"(d) : "v"(a), "v"(b), "v"(c));
    return d;
}
__device__ inline unsigned pkmul(unsigned a, unsigned b) {
    unsigned d;
    asm("v_pk_mul_f16 %0, %1, %2" : "=v"(d) : "v"(a), "v"(b));
    return d;
}
// bilinear blend of one 8-ch item (4 packed pairs) + per-channel scale -> 16B LDS write
__device__ inline void blend16(uint4 q0, uint4 q1, uint4 q2, uint4 q3,
                               uint2 cw, uint4 sp, char* dst) {
    unsigned o0 = pkmul_lo(q0.x, cw.x); o0 = pkfma_hi(q1.x, cw.x, o0);
    o0 = pkfma_lo(q2.x, cw.y, o0); o0 = pkfma_hi(q3.x, cw.y, o0); o0 = pkmul(o0, sp.x);
    unsigned o1 = pkmul_lo(q0.y, cw.x); o1 = pkfma_hi(q1.y, cw.x, o1);
    o1 = pkfma_lo(q2.y, cw.y, o1); o1 = pkfma_hi(q3.y, cw.y, o1); o1 = pkmul(o1, sp.y);
    unsigned o2 = pkmul_lo(q0.z, cw.x); o2 = pkfma_hi(q1.z, cw.x, o2);
    o2 = pkfma_lo(q2.z, cw.y, o2); o2 = pkfma_hi(q3.z, cw.y, o2); o2 = pkmul(o2, sp.z);
    unsigned o3 = pkmul_lo(q0.w, cw.x); o3 = pkfma_hi(q1.w, cw.x, o3);
    o3 = pkfma_lo(q2.w, cw.y, o3); o3 = pkfma_hi(q3.w, cw.y, o3); o3 = pkmul(o3, sp.w);
    *(uint4*)dst = make_uint4(o0, o1, o2, o3);
}

// ---------------- prep_xt + weight prep merged ----------------
// blocks [0,1568): NCHW f32 -> NHWC fp16 + fused channel sums (atomic into y)
// blocks [1568,1856): deform weights -> per-phase frag chunks (r10/r13 layout)
// blocks [1856,1892): offset weights -> 36 pre-swizzled 4KB tiles
__global__ __launch_bounds__(256) void prep_xt(const float* __restrict__ x,
                                               const float* __restrict__ w_conv,
                                               const float* __restrict__ w_off,
                                               unsigned short* __restrict__ x_t,
                                               unsigned short* __restrict__ wbf,
                                               unsigned short* __restrict__ wbo,
                                               float* __restrict__ y) {
    int blk = blockIdx.x;
    int tid = threadIdx.x;
    if (blk >= 1568) {
        int wb = blk - 1568;
        if (wb < 288) {
            int idx = wb * 256 + tid;            // 73728 items
            int lane = idx & 63;
            int f = (idx >> 6) & 3;
            int og = (idx >> 8) & 7;
            int t = idx >> 11;                   // 0..35
            int kk = t >> 2, cc = t & 3;
            int n = f >> 1, kh = f & 1;
            int o = og * 32 + n * 16 + (lane & 15);
            int cb2 = cc * 64 + kh * 32 + ((lane >> 4) << 3);
            short8 r;
            #pragma unroll
            for (int e = 0; e < 8; ++e) r[e] = (short)f2h(w_conv[(size_t)(o * 256 + cb2 + e) * 9 + kk]);
            *(short8*)(wbf + (size_t)idx * 8) = r;
        } else {
            int idx = (wb - 288) * 256 + tid;    // 9216
            int g = idx & 7;
            int o = (idx >> 3) & 31;
            int t = idx >> 8;
            int kk = t >> 2, cc = t & 3;
            int dst = (((o * 128 + g * 16) ^ ((o & 7) << 4)) >> 1);
            short8 r;
            #pragma unroll
            for (int e = 0; e < 8; ++e) {
                int c = cc * 64 + g * 8 + e;
                r[e] = (o < 18) ? (short)f2h(w_off[(size_t)(o * 256 + c) * 9 + kk]) : (short)0;
            }
            *(short8*)(wbo + (size_t)t * 2048 + dst) = r;
        }
        return;
    }
    __shared__ float t[64][65];
    int ct = blk & 3;
    int hwt = (blk >> 2) % 49;
    int b = blk / (4 * 49);
    int c0 = ct * 64, hw0 = hwt * 64;
    const float* xb = x + ((size_t)(b * CC + c0)) * HWH + hw0;
    #pragma unroll
    for (int it = 0; it < 16; ++it) {
        int idx = it * 256 + tid;
        int c = idx >> 6, px = idx & 63;
        t[c][px] = xb[(size_t)c * HWH + px];
    }
    __syncthreads();
    unsigned short* xo = x_t + ((size_t)(b * HWH + hw0)) * CC + c0;
    #pragma unroll
    for (int it = 0; it < 16; ++it) {
        int idx = it * 256 + tid;
        int px = idx >> 6, c = idx & 63;
        xo[(size_t)px * CC + c] = f2h(t[c][px]);
    }
    int c = tid >> 2, seg = tid & 3;
    float sum = 0.f;
    #pragma unroll
    for (int i = 0; i < 16; ++i) sum += t[c][seg * 16 + i];
    sum += __shfl_down(sum, 1);
    sum += __shfl_down(sum, 2);
    if (seg == 0) atomicAdd(&y[b * 256 + c0 + c], sum);
}

// inline SE: compute s[256] for batch b into s_out (LDS), using first 256 threads.
// Requires a block-wide barrier AFTER the call (caller provides).
__device__ inline void se_inline(int tid, int b, const float* __restrict__ y,
                                 const float* __restrict__ fc1, const float* __restrict__ fc2,
                                 float* __restrict__ h_lds, float* __restrict__ s_out) {
    if (tid < 256) {
        int r = tid >> 4, cseg = tid & 15;
        float part = 0.f;
        #pragma unroll
        for (int i = 0; i < 16; ++i)
            part += y[b * 256 + cseg * 16 + i] * fc1[r * 256 + cseg * 16 + i];
        part += __shfl_down(part, 8);
        part += __shfl_down(part, 4);
        part += __shfl_down(part, 2);
        part += __shfl_down(part, 1);
        if (cseg == 0) h_lds[r] = fmaxf(part * (1.0f / HWH), 0.f);
    }
    __syncthreads();
    if (tid < 256) {
        float acc = 0.f;
        #pragma unroll
        for (int rr = 0; rr < 16; ++rr) acc += h_lds[rr] * fc2[tid * 16 + rr];
        s_out[tid] = 1.0f / (1.0f + __expf(-acc));
    }
}

// ---------------- offset conv (fp16 MFMA) + fused SE + fused coord precompute ----------------
__global__ __launch_bounds__(256) void offset_mfma(const unsigned short* __restrict__ x_t,
                                                   const float* __restrict__ y,
                                                   const float* __restrict__ fc1,
                                                   const float* __restrict__ fc2,
                                                   const unsigned short* __restrict__ wbo,
                                                   const float* __restrict__ b_off,
                                                   int4* __restrict__ ci, uint2* __restrict__ cfh) {
    __shared__ __align__(16) char As[4][4096];
    __shared__ __align__(16) char Bs[4][4096];
    __shared__ float red[128 * 8];
    __shared__ float obuf[18 * 32];
    __shared__ float s_lds[256];
    __shared__ float h_lds[16];
    int blk = blockIdx.x;
    blk = (blk & 7) * 98 + (blk >> 3);
    int b = blk / 98;
    int hw0 = (blk % 98) * 32;
    int tid = threadIdx.x;
    int lane = tid & 63, wv = tid >> 6;
    int ks = wv >> 1, m = wv & 1;
    int r0 = lane & 15, kb = (lane >> 4) << 4;
    int px = tid >> 3, c8 = tid & 7;
    int hwp = hw0 + px;
    int hp = hwp / 56, wp_ = hwp - hp * 56;
    int awoff = (px * 128 + c8 * 16) ^ ((px & 7) << 4);
    f32x4 zero = {0.f, 0.f, 0.f, 0.f};
    f32x4 acc[2] = {zero, zero};

    se_inline(tid, b, y, fc1, fc2, h_lds, s_lds);
    __syncthreads();

    auto buildA = [&](int q, int r, int buf) {
        int t = q * 18 + r;
        int kk = t >> 2, cc = t & 3;
        int hh = hp + kk / 3 - 1, ww = wp_ + kk % 3 - 1;
        short8 v = {0, 0, 0, 0, 0, 0, 0, 0};
        if (hh >= 0 && hh < 56 && ww >= 0 && ww < 56)
            v = *(const short8*)(x_t + (((size_t)(b * HWH + hh * 56 + ww)) << 8) + cc * 64 + c8 * 8);
        const float* sp_ = &s_lds[cc * 64 + c8 * 8];
        unsigned p0 = pkrtz(h2f((unsigned short)v[0]) * sp_[0], h2f((unsigned short)v[1]) * sp_[1]);
        unsigned p1 = pkrtz(h2f((unsigned short)v[2]) * sp_[2], h2f((unsigned short)v[3]) * sp_[3]);
        unsigned p2 = pkrtz(h2f((unsigned short)v[4]) * sp_[4], h2f((unsigned short)v[5]) * sp_[5]);
        unsigned p3 = pkrtz(h2f((unsigned short)v[6]) * sp_[6], h2f((unsigned short)v[7]) * sp_[7]);
        *(uint4*)(As[q * 2 + buf] + awoff) = make_uint4(p0, p1, p2, p3);
    };
    auto stageB = [&](int q, int r, int buf) {
        int t = q * 18 + r;
        gl2lds16(wbo + (size_t)t * 2048 + tid * 8, Bs[q * 2 + buf] + (tid >> 6) * 1024);
    };

    stageB(0, 0, 0); stageB(1, 0, 0);
    buildA(0, 0, 0); buildA(1, 0, 0);
    __syncthreads();

    #pragma unroll 2
    for (int r = 0; r < 18; ++r) {
        int cur = r & 1;
        if (r < 17) {
            stageB(0, r + 1, cur ^ 1); stageB(1, r + 1, cur ^ 1);
            buildA(0, r + 1, cur ^ 1); buildA(1, r + 1, cur ^ 1);
        }
        h16x8 a[2];
        #pragma unroll
        for (int kh = 0; kh < 2; ++kh) {
            int row = m * 16 + r0;
            int ao = (row * 128 + kh * 64 + kb) ^ ((row & 7) << 4);
            a[kh] = __builtin_bit_cast(h16x8, *(const short8*)(As[ks * 2 + cur] + ao));
        }
        #pragma unroll
        for (int n = 0; n < 2; ++n)
            #pragma unroll
            for (int kh = 0; kh < 2; ++kh) {
                int brow = n * 16 + r0;
                int bo = (brow * 128 + kh * 64 + kb) ^ ((brow & 7) << 4);
                h16x8 bv = __builtin_bit_cast(h16x8, *(const short8*)(Bs[ks * 2 + cur] + bo));
                acc[n] = __builtin_amdgcn_mfma_f32_16x16x32_f16(a[kh], bv, acc[n], 0, 0, 0);
            }
        __syncthreads();
    }

    if (ks == 1) {
        #pragma unroll
        for (int n = 0; n < 2; ++n)
            *(f32x4*)&red[(m * 64 + lane) * 8 + n * 4] = acc[n];
    }
    __syncthreads();
    if (ks == 0) {
        #pragma unroll
        for (int n = 0; n < 2; ++n) {
            f32x4 o2 = *(const f32x4*)&red[(m * 64 + lane) * 8 + n * 4];
            acc[n] += o2;
            int o = n * 16 + r0;
            if (o < 18) {
                float bia = b_off[o];
                #pragma unroll
                for (int j = 0; j < 4; ++j)
                    obuf[o * 32 + m * 16 + ((lane >> 4) << 2) + j] = acc[n][j] + bia;
            }
        }
    }
    __syncthreads();
    // ---- fused coords: 32px x 9kk ----
    for (int i = tid; i < 288; i += 256) {
        int pxi = i & 31, kk = i >> 5;
        int hw = hw0 + pxi;
        int h = hw / 56, w = hw - h * 56;
        float dy = obuf[(kk * 2) * 32 + pxi];
        float dx = obuf[(kk * 2 + 1) * 32 + pxi];
        float ys = (float)(h - 1 + kk / 3) + dy;
        float xs = (float)(w - 1 + kk % 3) + dx;
        float y0f = floorf(ys), x0f = floorf(xs);
        float wy = ys - y0f, wx = xs - x0f;
        int y0 = (int)y0f, x0 = (int)x0f;
        int bi[4]; float wt[4];
        #pragma unroll
        for (int j = 0; j < 4; ++j) {
            int yj = y0 + (j >> 1), xj = x0 + (j & 1);
            bool val = yj >= 0 && yj < 56 && xj >= 0 && xj < 56;
            int yc = min(max(yj, 0), 55), xc = min(max(xj, 0), 55);
            wt[j] = val ? ((j >> 1) ? wy : 1.f - wy) * ((j & 1) ? wx : 1.f - wx) : 0.f;
            bi[j] = (b * HWH + yc * 56 + xc) << 8;
        }
        int idx = (b * 9 + kk) * HWH + hw;
        ci[idx] = make_int4(bi[0], bi[1], bi[2], bi[3]);
        cfh[idx] = make_uint2(pkrtz(wt[0], wt[1]), pkrtz(wt[2], wt[3]));
    }
}

// ---------------- deformable conv: 392 blocks x 512 thr, 64px x 256o, fused SE ----------------
// r14 core: 4-buffer A pipeline, blend distance 2, corner distance 4, barrier
// every 2 phases; setprio around MFMA cluster. (r15 = empirical optimum.)
__global__ __launch_bounds__(512) void deform_mfma(const unsigned short* __restrict__ x_t,
                                                   const float* __restrict__ y,
                                                   const float* __restrict__ fc1,
                                                   const float* __restrict__ fc2,
                                                   const int4* __restrict__ ci,
                                                   const uint2* __restrict__ cfh,
                                                   const unsigned short* __restrict__ wbf,
                                                   const float* __restrict__ b_conv,
                                                   float* __restrict__ out) {
    __shared__ __align__(16) char As[32768];     // 4 x 8KB (64px x 128B)
    __shared__ __align__(16) float s_buf[256];
    __shared__ float h_lds[16];
    int blk = blockIdx.x;
    blk = (blk & 7) * 49 + (blk >> 3);           // bijective XCD swizzle (392 = 8*49)
    int b = blk / 49;
    int hw0 = (blk % 49) * 64;
    int tid = threadIdx.x;
    int lane = tid & 63, og = tid >> 6;
    int px = tid >> 3, cg = tid & 7;             // A-build: 64px x 8 groups of 8ch (16B)
    int r0 = lane & 15, kb = (lane >> 4) << 4;
    int awoff = px * 128 + (cg * 16 ^ ((px & 7) << 4));
    int cidx0 = b * 9 * HWH + hw0 + px;
    const unsigned short* wbB = wbf + og * 2048 + lane * 8;

    se_inline(tid, b, y, fc1, fc2, h_lds, s_buf);
    __syncthreads();

    uint4 sp4[4];
    #pragma unroll
    for (int cc = 0; cc < 4; ++cc) {
        float4 s0 = *(const float4*)&s_buf[cc * 64 + cg * 8];
        float4 s1 = *(const float4*)&s_buf[cc * 64 + cg * 8 + 4];
        sp4[cc] = make_uint4(pkrtz(s0.x, s0.y), pkrtz(s0.z, s0.w), pkrtz(s1.x, s1.y), pkrtz(s1.z, s1.w));
    }

    f32x4 zero = {0.f, 0.f, 0.f, 0.f};
    f32x4 acc[4][2];
    #pragma unroll
    for (int m = 0; m < 4; ++m)
        #pragma unroll
        for (int n = 0; n < 2; ++n) acc[m][n] = zero;

    int4 cbL = ci[cidx0];
    uint2 cwB = cfh[cidx0];
    int4 cbN = ci[cidx0 + HWH];
    uint2 cwM = cfh[cidx0 + HWH];
    uint2 cwP = cwM;

    uint4 crn0[4], crn1[4];
    short8 bv[4];
    const unsigned short* wbK = wbB + 16384;     // ptr to B(1)

    // ---- prologue: blend A(0),A(1) -> As[0],As[1]; crn0<-cc2, crn1<-cc3; bv(0) ----
    {
        uint4 q[4];
        int c00 = cg * 8;
        q[0] = *(const uint4*)(x_t + cbL.x + c00);
        q[1] = *(const uint4*)(x_t + cbL.y + c00);
        q[2] = *(const uint4*)(x_t + cbL.z + c00);
        q[3] = *(const uint4*)(x_t + cbL.w + c00);
        int c02 = 128 + cg * 8;
        crn0[0] = *(const uint4*)(x_t + cbL.x + c02);
        crn0[1] = *(const uint4*)(x_t + cbL.y + c02);
        crn0[2] = *(const uint4*)(x_t + cbL.z + c02);
        crn0[3] = *(const uint4*)(x_t + cbL.w + c02);
        int c03 = 192 + cg * 8;
        crn1[0] = *(const uint4*)(x_t + cbL.x + c03);
        crn1[1] = *(const uint4*)(x_t + cbL.y + c03);
        crn1[2] = *(const uint4*)(x_t + cbL.z + c03);
        crn1[3] = *(const uint4*)(x_t + cbL.w + c03);
        #pragma unroll
        for (int f = 0; f < 4; ++f) bv[f] = *(const short8*)(wbB + f * 512);
        blend16(q[0], q[1], q[2], q[3], cwB, sp4[0], As + awoff);
        int c01 = 64 + cg * 8;
        q[0] = *(const uint4*)(x_t + cbL.x + c01);
        q[1] = *(const uint4*)(x_t + cbL.y + c01);
        q[2] = *(const uint4*)(x_t + cbL.z + c01);
        q[3] = *(const uint4*)(x_t + cbL.w + c01);
        blend16(q[0], q[1], q[2], q[3], cwB, sp4[1], As + 8192 + awoff);
    }
    __syncthreads();

#define PHASE(CCV, CRN) { \
    constexpr int CCc = (CCV); \
    if (CCc == 0) cbL = cbN; \
    h16x8 a_[4][2]; \
    { constexpr int tb_ = CCc * 8192; \
      _Pragma("unroll") for (int m_ = 0; m_ < 4; ++m_) \
      _Pragma("unroll") for (int kh_ = 0; kh_ < 2; ++kh_) { \
        int row_ = m_ * 16 + r0; \
        int ao_ = row_ * 128 + ((kh_ * 64 + kb) ^ ((row_ & 7) << 4)); \
        a_[m_][kh_] = __builtin_bit_cast(h16x8, *(const short8*)(As + tb_ + ao_)); } } \
    __builtin_amdgcn_s_setprio(1); \
    _Pragma("unroll") for (int n_ = 0; n_ < 2; ++n_) \
      _Pragma("unroll") for (int kh_ = 0; kh_ < 2; ++kh_) \
        _Pragma("unroll") for (int m_ = 0; m_ < 4; ++m_) \
          acc[m_][n_] = __builtin_amdgcn_mfma_f32_16x16x32_f16(a_[m_][kh_], __builtin_bit_cast(h16x8, bv[n_ * 2 + kh_]), acc[m_][n_], 0, 0, 0); \
    __builtin_amdgcn_s_setprio(0); \
    if (kk < 8 || CCc < 3) { \
        _Pragma("unroll") for (int f_ = 0; f_ < 4; ++f_) bv[f_] = *(const short8*)(wbK + f_ * 512); } \
    wbK += 16384; \
    if (CCc == 2) { cwB = cwM; cwM = cwP; } \
    if (kk < 8 || CCc < 2) { \
        blend16(CRN[0], CRN[1], CRN[2], CRN[3], cwB, sp4[(CCc + 2) & 3], \
                As + ((CCc + 2) & 3) * 8192 + awoff); } \
    if (kk < 8) { \
        constexpr int c0_ = CCc * 64; \
        CRN[0] = *(const uint4*)(x_t + cbL.x + c0_ + cg * 8); \
        CRN[1] = *(const uint4*)(x_t + cbL.y + c0_ + cg * 8); \
        CRN[2] = *(const uint4*)(x_t + cbL.z + c0_ + cg * 8); \
        CRN[3] = *(const uint4*)(x_t + cbL.w + c0_ + cg * 8); } \
    if (CCc == 1 && kk <= 6) { \
        int cidx = cidx0 + (kk + 2) * HWH; \
        cbN = ci[cidx]; cwP = cfh[cidx]; } \
    if (CCc & 1) __syncthreads(); }

    #pragma unroll 1
    for (int kk = 0; kk < 9; ++kk) {
        PHASE(0, crn0);
        PHASE(1, crn1);
        PHASE(2, crn0);
        PHASE(3, crn1);
    }
#undef PHASE

    // ---- epilogue: bias + tanh, NCHW float4 stores ----
    #pragma unroll
    for (int n = 0; n < 2; ++n) {
        int o = og * 32 + n * 16 + r0;
        float bia = b_conv[o];
        #pragma unroll
        for (int m = 0; m < 4; ++m) {
            int pxo = hw0 + m * 16 + ((lane >> 4) << 2);
            float4 v;
            v.x = fast_tanh(acc[m][n][0] + bia);
            v.y = fast_tanh(acc[m][n][1] + bia);
            v.z = fast_tanh(acc[m][n][2] + bia);
            v.w = fast_tanh(acc[m][n][3] + bia);
            *(float4*)(out + ((size_t)(b * OO + o)) * HWH + pxo) = v;
        }
    }
}

extern "C" void kernel_launch(void* const* d_in, const int* in_sizes, int n_in,
                              void* d_out, int out_size, void* d_ws, size_t ws_size,
                              hipStream_t stream) {
    const float* x      = (const float*)d_in[0];
    const float* w_off  = (const float*)d_in[1];
    const float* b_off  = (const float*)d_in[2];
    const float* w_conv = (const float*)d_in[3];
    const float* b_conv = (const float*)d_in[4];
    const float* fc1    = (const float*)d_in[5];
    const float* fc2    = (const float*)d_in[6];
    float* out = (float*)d_out;
    float* ws  = (float*)d_ws;

    float* y = ws;                                             // 2048 f32
    unsigned short* x_t = (unsigned short*)(y + 2048);         // 6,422,528 shorts (fp16)
    unsigned short* wbo = x_t + 6422528;                       // 73,728 shorts
    unsigned short* wbf = wbo + 73728;                         // 589,824 shorts (36-phase frag layout)
    int4*  ci  = (int4*)(wbf + 589824);                        // 225,792 int4
    uint2* cfh = (uint2*)(ci + 225792);                        // 225,792 uint2

    hipMemsetAsync(y, 0, 2048 * sizeof(float), stream);
    prep_xt<<<1892, 256, 0, stream>>>(x, w_conv, w_off, x_t, wbf, wbo, y);
    offset_mfma<<<BB * 98, 256, 0, stream>>>(x_t, y, fc1, fc2, wbo, b_off, ci, cfh);
    deform_mfma<<<BB * 49, 512, 0, stream>>>(x_t, y, fc1, fc2, ci, cfh, wbf, b_conv, out);
}